// Round 3
// baseline (1690.636 us; speedup 1.0000x reference)
//
#include <hip/hip_runtime.h>
#include <math.h>

#define EPSC 1e-8f
#define TOPK 5

typedef _Float16 half8_t __attribute__((ext_vector_type(8)));
typedef float f32x4 __attribute__((ext_vector_type(4)));

__device__ __forceinline__ bool better(float va, int ia, float vb, int ib) {
    return (va > vb) || (va == vb && ia < ib);
}

// insert (v,gi) into sorted-desc top-5 (lv,li)
__device__ __forceinline__ void ins5(float v, int gi, float lv[TOPK], int li[TOPK]) {
    if (better(v, gi, lv[4], li[4])) {
        lv[4] = v; li[4] = gi;
#pragma unroll
        for (int p = 4; p > 0; --p) {
            if (better(lv[p], li[p], lv[p - 1], li[p - 1])) {
                float tv = lv[p]; lv[p] = lv[p - 1]; lv[p - 1] = tv;
                int ti = li[p]; li[p] = li[p - 1]; li[p - 1] = ti;
            }
        }
    }
}

// async 16B global->LDS copy (DMA, no VGPR roundtrip); dest = wave-uniform base + lane*16
__device__ __forceinline__ void gload16(const void* g, void* l) {
    __builtin_amdgcn_global_load_lds(
        (const __attribute__((address_space(1))) unsigned int*)g,
        (__attribute__((address_space(3))) unsigned int*)l, 16, 0, 0);
}

// ---------------- center = mean(spatial_weights, axis=0) ----------------
__global__ void k_center(const float* __restrict__ sw, int H, float* __restrict__ center) {
    int tid = threadIdx.x;  // 64
    float sx = 0.f, sy = 0.f;
    for (int r = tid; r < H; r += 64) { sx += sw[2 * r]; sy += sw[2 * r + 1]; }
    for (int o = 32; o > 0; o >>= 1) { sx += __shfl_down(sx, o); sy += __shfl_down(sy, o); }
    if (tid == 0) { center[0] = sx / (float)H; center[1] = sy / (float)H; }
}

// ---------------- normalize queries + split to f16 hi/lo in plane-split frag-linear layout ----------------
// plane p (0=hi,1=lo) stride PS=16*KCH*512 f16;
// within plane: (qt*KCH + kc)*512 + (quad*16 + (b&15))*8 + j   where d = kc*32 + quad*8 + j
__global__ void k_qprep(const float* __restrict__ q, _Float16* __restrict__ Aglob, int B, int D) {
    int b = blockIdx.x;
    int tid = threadIdx.x;  // 128
    const int KCH = D >> 5;
    const int PS = 16 * KCH * 512;
    float ss = 0.f;
    for (int d = tid; d < D; d += 128) { float v = q[(size_t)b * D + d]; ss = fmaf(v, v, ss); }
    for (int o = 32; o > 0; o >>= 1) ss += __shfl_down(ss, o);
    __shared__ float w2[2];
    if ((tid & 63) == 0) w2[tid >> 6] = ss;
    __syncthreads();
    float inv = 1.f / fmaxf(sqrtf(w2[0] + w2[1]), EPSC);
    int qt = b >> 4, nl = b & 15;
    for (int d = tid; d < D; d += 128) {
        float v = q[(size_t)b * D + d] * inv;
        _Float16 hi = (_Float16)v;
        _Float16 lo = (_Float16)(v - (float)hi);
        int kc = d >> 5, r = d & 31, quad = r >> 3, j = r & 7;
        int idx = (qt * KCH + kc) * 512 + (quad * 16 + nl) * 8 + j;
        Aglob[idx] = hi;
        Aglob[PS + idx] = lo;
    }
}

// convert 8 fp32 -> f16 hi/lo planes + fused sum-of-squares, write to LDS
__device__ __forceinline__ void convwrite(float4 v0, float4 v1, _Float16* Bh, _Float16* Bl,
                                          int off, float& ss) {
    float vv[8] = {v0.x, v0.y, v0.z, v0.w, v1.x, v1.y, v1.z, v1.w};
    half8_t hv, lov;
#pragma unroll
    for (int j = 0; j < 8; ++j) {
        float f = vv[j];
        ss = fmaf(f, f, ss);
        _Float16 h = (_Float16)f;
        hv[j] = h;
        lov[j] = (_Float16)(f - (float)h);
    }
    *(half8_t*)(Bh + off) = hv;
    *(half8_t*)(Bl + off) = lov;
}

// ---------------- main: split-f16 MFMA sim GEMM + fused norms + per-row top-5 ----------------
// grid: ceil(M/128), 256 threads (4 waves). Block: 256 queries x 128 mem rows (2 chunks of 64).
// A staged per-kc via global_load_lds (linear copy); B double-buffered, prefetch under MFMA.
__launch_bounds__(256, 2)
__global__ void k_sim_topk(const _Float16* __restrict__ Aglob, const float* __restrict__ mem,
                           const float* __restrict__ coords, const float* __restrict__ center,
                           float* __restrict__ candV, int* __restrict__ candI,
                           int M, int D) {
    __shared__ __align__(16) char smem[50688];
    _Float16* Ah = (_Float16*)smem;              // [16 qt][512 f16]  16 KB (plane hi)
    _Float16* Al = Ah + 8192;                    //                   16 KB (plane lo)
    _Float16* Bbuf = (_Float16*)(smem + 32768);  // 2 bufs x (Bh 2048 + Bl 2048 f16) = 16 KB
    float* Cs = (float*)smem;                    // epilogue overlay: 4 waves x 32 x 68 fp32 = 34816 B
    float* ssbuf  = (float*)(smem + 49152);      // 256 fp32
    float* colinv = ssbuf + 256;                 // 64
    float* colact = colinv + 64;                 // 64

    const int tid = threadIdx.x;
    const int lane = tid & 63, w = tid >> 6;
    const int nB = tid >> 2, qB = tid & 3;   // B staging: mem-row nB (0..63), k-octet qB
    const int KCH = D >> 5;
    const int PS = 16 * KCH * 512;
    const int n0 = blockIdx.x * 128;
    const float cx = center[0], cy = center[1];
    const int quad = lane >> 4, c15 = lane & 15;
    const int rr = lane & 31, hh = lane >> 5;
    const int woff = ((nB >> 4) * 64 + qB * 16 + (nB & 15)) * 8;  // f16 offset in B plane

    float lv[TOPK]; int li[TOPK];
#pragma unroll
    for (int k = 0; k < TOPK; ++k) { lv[k] = -INFINITY; li[k] = 0x7fffffff; }

    for (int ch = 0; ch < 2; ++ch) {
        const int base = n0 + ch * 64;
        const int brow = base + nB;
        const bool bvalid = brow < M;
        const float* mrow = mem + (size_t)brow * D;
        f32x4 acc[4][4];
#pragma unroll
        for (int rt = 0; rt < 4; ++rt)
#pragma unroll
            for (int ct = 0; ct < 4; ++ct) acc[rt][ct] = (f32x4){0.f, 0.f, 0.f, 0.f};
        float ss = 0.f;

        // prologue: stage B for kc=0 into buf 0
        {
            float4 v0 = {0.f, 0.f, 0.f, 0.f}, v1 = {0.f, 0.f, 0.f, 0.f};
            if (bvalid) {
                const float* p0 = mrow + qB * 8;
                v0 = *(const float4*)p0;
                v1 = *(const float4*)(p0 + 4);
            }
            convwrite(v0, v1, Bbuf, Bbuf + 2048, woff, ss);
        }

        for (int kc = 0; kc < KCH; ++kc) {
            const int p = kc & 1;
            __syncthreads();  // (a) prev frag reads done (A overwrite safe); B[p] writes visible
            // A stage: 8 x 16B per thread, pure linear async copy global->LDS.
            // u = tid + i*256: LDS byte u*16; per wave-issue dest = uniform base + lane*16.
#pragma unroll
            for (int i = 0; i < 8; ++i) {
                int u = tid + i * 256;
                int pl = u >> 10, rem = u & 1023, qt = rem >> 6, t = u & 63;
                gload16(Aglob + (size_t)pl * PS + ((size_t)qt * KCH + kc) * 512 + t * 8,
                        smem + (size_t)u * 16);
            }
            __syncthreads();  // (b) A staged (barrier drains vmcnt/lgkm)
            // A fragments from LDS (conflict-free: lane-contiguous 16B)
            half8_t ah[4], al[4];
#pragma unroll
            for (int rt = 0; rt < 4; ++rt) {
                int qt = w * 4 + rt;
                ah[rt] = *(half8_t*)(Ah + qt * 512 + lane * 8);
                al[rt] = *(half8_t*)(Al + qt * 512 + lane * 8);
            }
            // B prefetch for kc+1 issued here: HBM latency hides under MFMA phase,
            // consumed (vmcnt wait) only at convwrite after the MFMAs.
            float4 n0v = {0.f, 0.f, 0.f, 0.f}, n1v = {0.f, 0.f, 0.f, 0.f};
            if (kc + 1 < KCH && bvalid) {
                const float* pn = mrow + (kc + 1) * 32 + qB * 8;
                n0v = *(const float4*)pn;
                n1v = *(const float4*)(pn + 4);
            }
            // B fragments + MFMA (hh, hl, lh products)
            const _Float16* Bh = Bbuf + p * 4096;
            const _Float16* Bl = Bh + 2048;
#pragma unroll
            for (int ct = 0; ct < 4; ++ct) {
                half8_t bh = *(const half8_t*)(Bh + (ct * 64 + lane) * 8);
                half8_t bl = *(const half8_t*)(Bl + (ct * 64 + lane) * 8);
#pragma unroll
                for (int rt = 0; rt < 4; ++rt) {
                    acc[rt][ct] = __builtin_amdgcn_mfma_f32_16x16x32_f16(ah[rt], bh, acc[rt][ct], 0, 0, 0);
                    acc[rt][ct] = __builtin_amdgcn_mfma_f32_16x16x32_f16(ah[rt], bl, acc[rt][ct], 0, 0, 0);
                    acc[rt][ct] = __builtin_amdgcn_mfma_f32_16x16x32_f16(al[rt], bh, acc[rt][ct], 0, 0, 0);
                }
            }
            // convert + write next B into buf[p^1]
            if (kc + 1 < KCH) {
                _Float16* Bhn = Bbuf + (p ^ 1) * 4096;
                convwrite(n0v, n1v, Bhn, Bhn + 2048, woff, ss);
            }
        }

        // column stats
        ssbuf[tid] = ss;
        __syncthreads();  // all frag reads done before Cs overlay; ssbuf visible
        if (tid < 64) {
            float s = ssbuf[tid * 4] + ssbuf[tid * 4 + 1] + ssbuf[tid * 4 + 2] + ssbuf[tid * 4 + 3];
            colinv[tid] = 1.f / fmaxf(sqrtf(s), EPSC);
            int m = base + tid;
            float act = -INFINITY;
            if (m < M) {
                float dx = coords[2 * (size_t)m] - cx;
                float dy = coords[2 * (size_t)m + 1] - cy;
                act = 1.f / (1.f + sqrtf(dx * dx + dy * dy));
            }
            colact[tid] = act;
        }
        __syncthreads();

        // epilogue: two 32-row passes; per pass each row scanned by 2 lanes (32 cols each),
        // lists merged via shfl_xor(32) with snapshot; owner lane absorbs.
        float* Cw = Cs + w * (32 * 68);
#pragma unroll
        for (int ps = 0; ps < 2; ++ps) {
#pragma unroll
            for (int rt2 = 0; rt2 < 2; ++rt2) {
                const int rt = 2 * ps + rt2;
#pragma unroll
                for (int ct = 0; ct < 4; ++ct) {
                    const int c = ct * 16 + c15;
                    const float inv = colinv[c], act = colact[c];
#pragma unroll
                    for (int i = 0; i < 4; ++i) {
                        Cw[(rt2 * 16 + quad * 4 + i) * 68 + c] = fmaf(acc[rt][ct][i], inv, act);
                    }
                }
            }
            // same-wave write->read: no barrier needed
            float tv5[TOPK]; int ti5[TOPK];
#pragma unroll
            for (int k = 0; k < TOPK; ++k) { tv5[k] = -INFINITY; ti5[k] = 0x7fffffff; }
            const float* Crow = Cw + rr * 68 + hh * 32;
            for (int j = 0; j < 32; ++j) {
                const int cc = (j + lane) & 31;
                ins5(Crow[cc], base + hh * 32 + cc, tv5, ti5);
            }
            // snapshot partner's list FIRST (both sides mutate during merge)
            float pv[TOPK]; int pi[TOPK];
#pragma unroll
            for (int k = 0; k < TOPK; ++k) {
                pv[k] = __shfl_xor(tv5[k], 32);
                pi[k] = __shfl_xor(ti5[k], 32);
            }
#pragma unroll
            for (int k = 0; k < TOPK; ++k) ins5(pv[k], pi[k], tv5, ti5);
            if (hh == ps) {  // owner lane: query offset = ps*32 + rr == lane
#pragma unroll
                for (int k = 0; k < TOPK; ++k) ins5(tv5[k], ti5[k], lv, li);
            }
        }
        __syncthreads();  // epilogue reads done before next chunk restages A/B (overlap Cs)
    }
    // per-q candidates: q = w*64 + lane
    size_t cb = ((size_t)blockIdx.x * 256 + (w * 64 + lane)) * TOPK;
#pragma unroll
    for (int k = 0; k < TOPK; ++k) { candV[cb + k] = lv[k]; candI[cb + k] = li[k]; }
}

// ---------------- merge per-tile candidates -> global top-5 (sorted desc) ----------------
__global__ void k_merge(const float* __restrict__ candV, const int* __restrict__ candI,
                        int ntiles, int B, int* __restrict__ topk) {
    int b = blockIdx.x;
    int tid = threadIdx.x;  // 256
    float lv[TOPK]; int li[TOPK];
#pragma unroll
    for (int k = 0; k < TOPK; ++k) { lv[k] = -INFINITY; li[k] = 0x7fffffff; }
    for (int t = tid; t < ntiles; t += 256) {
        size_t base = ((size_t)t * B + b) * TOPK;
#pragma unroll
        for (int k = 0; k < TOPK; ++k) {
            float v = candV[base + k]; int gi = candI[base + k];
            if (better(v, gi, lv[4], li[4])) {
                lv[4] = v; li[4] = gi;
#pragma unroll
                for (int p = 4; p > 0; --p) {
                    if (better(lv[p], li[p], lv[p - 1], li[p - 1])) {
                        float tv = lv[p]; lv[p] = lv[p - 1]; lv[p - 1] = tv;
                        int ti = li[p]; li[p] = li[p - 1]; li[p - 1] = ti;
                    }
                }
            }
        }
    }
    __shared__ float sv[256 * TOPK];
    __shared__ int si[256 * TOPK];
#pragma unroll
    for (int k = 0; k < TOPK; ++k) { sv[tid * TOPK + k] = lv[k]; si[tid * TOPK + k] = li[k]; }
    __syncthreads();
    __shared__ float rv[256];
    __shared__ int ri[256], rp[256];
    for (int round = 0; round < TOPK; ++round) {
        float bv = -INFINITY; int bi = 0x7fffffff, bp = -1;
        for (int p = tid; p < 256 * TOPK; p += 256) {
            if (better(sv[p], si[p], bv, bi)) { bv = sv[p]; bi = si[p]; bp = p; }
        }
        rv[tid] = bv; ri[tid] = bi; rp[tid] = bp;
        __syncthreads();
        for (int st = 128; st > 0; st >>= 1) {
            if (tid < st) {
                if (better(rv[tid + st], ri[tid + st], rv[tid], ri[tid])) {
                    rv[tid] = rv[tid + st]; ri[tid] = ri[tid + st]; rp[tid] = rp[tid + st];
                }
            }
            __syncthreads();
        }
        if (tid == 0) {
            topk[b * TOPK + round] = ri[0];
            sv[rp[0]] = -INFINITY;
            si[rp[0]] = 0x7fffffff;
        }
        __syncthreads();
    }
}

// ---------------- gather RNN inputs: INP[b*6+t][D] ----------------
__global__ void k_gather(const float* __restrict__ q, const float* __restrict__ mem,
                         const int* __restrict__ topk, float* __restrict__ inp, int D) {
    int r = blockIdx.x;          // 0..B*6-1
    int b = r / 6, t = r - b * 6;
    int tid = threadIdx.x;       // 96 (D/4)
    const float* src = (t == 0) ? (q + (size_t)b * D)
                                : (mem + (size_t)topk[b * TOPK + (t - 1)] * D);
    *(float4*)&inp[(size_t)r * D + tid * 4] = *(const float4*)&src[tid * 4];
}

// ---------------- generic 64x64-tile fp32 GEMM: C = act(A @ W^T + bias) ----------------
// mode 0: dst = v (xproj);  mode 1: dst = sigmoid(v) (gate)
__launch_bounds__(256)
__global__ void k_tail_gemm(const float* __restrict__ A, const float* __restrict__ W,
                            const float* __restrict__ bias,
                            float* __restrict__ dst, int K, int ldc, int mode) {
    __shared__ float As[16 * 68], Ws[16 * 68];
    const int r0 = blockIdx.x * 64, c0 = blockIdx.y * 64;
    const int tid = threadIdx.x;
    float acc[4][4];
#pragma unroll
    for (int i = 0; i < 4; ++i)
#pragma unroll
        for (int j = 0; j < 4; ++j) acc[i][j] = 0.f;
    const int lr = tid >> 2, lk4 = (tid & 3) * 4;
    for (int k0 = 0; k0 < K; k0 += 16) {
        __syncthreads();
        float4 av = *(const float4*)&A[(size_t)(r0 + lr) * K + k0 + lk4];
        float4 wv = *(const float4*)&W[(size_t)(c0 + lr) * K + k0 + lk4];
        As[(lk4 + 0) * 68 + lr] = av.x; As[(lk4 + 1) * 68 + lr] = av.y;
        As[(lk4 + 2) * 68 + lr] = av.z; As[(lk4 + 3) * 68 + lr] = av.w;
        Ws[(lk4 + 0) * 68 + lr] = wv.x; Ws[(lk4 + 1) * 68 + lr] = wv.y;
        Ws[(lk4 + 2) * 68 + lr] = wv.z; Ws[(lk4 + 3) * 68 + lr] = wv.w;
        __syncthreads();
#pragma unroll
        for (int k = 0; k < 16; ++k) {
            float4 a4 = *(float4*)&As[k * 68 + (tid >> 4) * 4];
            float4 b4 = *(float4*)&Ws[k * 68 + (tid & 15) * 4];
            float a[4] = {a4.x, a4.y, a4.z, a4.w};
            float bb[4] = {b4.x, b4.y, b4.z, b4.w};
#pragma unroll
            for (int i = 0; i < 4; ++i)
#pragma unroll
                for (int j = 0; j < 4; ++j) acc[i][j] = fmaf(a[i], bb[j], acc[i][j]);
        }
    }
    const int tr = (tid >> 4) * 4, tc = (tid & 15) * 4;
#pragma unroll
    for (int i = 0; i < 4; ++i) {
        int r = r0 + tr + i;
#pragma unroll
        for (int j = 0; j < 4; ++j) {
            int c = c0 + tc + j;
            float v = acc[i][j] + bias[c];
            dst[(size_t)r * ldc + c] = (mode == 1) ? 1.f / (1.f + expf(-v)) : v;
        }
    }
}

// ---------------- fused 6-step RNN + gate mix (row-independent recurrence) ----------------
// grid: B/4 blocks, 256 threads (4 waves). Block rows [blk*4, +4).
// wave w owns cols [w*128, w*128+128); lane owns 2 cols c = w*128 + lane*2.
__launch_bounds__(256)
__global__ void k_rnn(const float* __restrict__ xp, const float* __restrict__ W_hh,
                      const float* __restrict__ b_hh, const float* __restrict__ gate,
                      float* __restrict__ out, int H) {
    __shared__ float hs[4][512];
    const int tid = threadIdx.x, lane = tid & 63, w = tid >> 6;
    const int b0 = blockIdx.x * 4;
    const int c0 = w * 128 + lane * 2;
    const float bh0 = b_hh[c0], bh1 = b_hh[c0 + 1];
    const float* w0p = W_hh + (size_t)c0 * H;
    const float* w1p = w0p + H;
    for (int t = 0; t < 6; ++t) {
        float acc[4][2];
#pragma unroll
        for (int r = 0; r < 4; ++r) {
            const float* xr = xp + ((size_t)(b0 + r) * 6 + t) * H;
            acc[r][0] = xr[c0] + bh0;
            acc[r][1] = xr[c0 + 1] + bh1;
        }
        if (t > 0) {
            for (int k = 0; k < H; k += 4) {
                float4 a0 = *(const float4*)(w0p + k);
                float4 a1 = *(const float4*)(w1p + k);
#pragma unroll
                for (int r = 0; r < 4; ++r) {
                    float4 h4 = *(const float4*)&hs[r][k];
                    acc[r][0] = fmaf(h4.x, a0.x, acc[r][0]);
                    acc[r][0] = fmaf(h4.y, a0.y, acc[r][0]);
                    acc[r][0] = fmaf(h4.z, a0.z, acc[r][0]);
                    acc[r][0] = fmaf(h4.w, a0.w, acc[r][0]);
                    acc[r][1] = fmaf(h4.x, a1.x, acc[r][1]);
                    acc[r][1] = fmaf(h4.y, a1.y, acc[r][1]);
                    acc[r][1] = fmaf(h4.z, a1.z, acc[r][1]);
                    acc[r][1] = fmaf(h4.w, a1.w, acc[r][1]);
                }
            }
        }
        __syncthreads();  // all reads of hs (state t-1) done before overwrite
        if (t < 5) {
#pragma unroll
            for (int r = 0; r < 4; ++r) {
                hs[r][c0]     = tanhf(acc[r][0]);
                hs[r][c0 + 1] = tanhf(acc[r][1]);
            }
        } else {
#pragma unroll
            for (int r = 0; r < 4; ++r) {
                const int b = b0 + r;
                const float* xq = xp + ((size_t)b * 6 + 0) * H;
#pragma unroll
                for (int j = 0; j < 2; ++j) {
                    float hn = tanhf(acc[r][j]);
                    float g = gate[(size_t)b * H + c0 + j];
                    out[(size_t)b * H + c0 + j] = g * hn + (1.f - g) * xq[c0 + j];
                }
            }
        }
        __syncthreads();  // new hs visible before next step's reads
    }
}

extern "C" void kernel_launch(void* const* d_in, const int* in_sizes, int n_in,
                              void* d_out, int out_size, void* d_ws, size_t ws_size,
                              hipStream_t stream) {
    const float* query  = (const float*)d_in[0];
    const float* mem    = (const float*)d_in[1];
    const float* coords = (const float*)d_in[2];
    const float* sw     = (const float*)d_in[3];
    const float* W_ih   = (const float*)d_in[4];
    const float* b_ih   = (const float*)d_in[5];
    const float* W_hh   = (const float*)d_in[6];
    const float* b_hh   = (const float*)d_in[7];
    const float* gate_W = (const float*)d_in[8];
    const float* gate_b = (const float*)d_in[9];

    const int H = in_sizes[5];           // 512
    const int D = in_sizes[4] / H;       // 384
    const int B = in_sizes[0] / D;       // 256
    const int M = in_sizes[1] / D;       // 200000
    const int KCH = D >> 5;
    const int ntiles = (M + 127) / 128;  // 1563

    float* Wf = (float*)d_ws;
    size_t off = 0;
    _Float16* Aglob = (_Float16*)Wf;     off += (size_t)2 * 16 * KCH * 512 / 2;  // f16 elems /2 = floats
    float* center = Wf + off; off += 4;
    float* candV  = Wf + off; off += (size_t)ntiles * B * TOPK;
    int*   candI  = (int*)(Wf + off); off += (size_t)ntiles * B * TOPK;
    int*   topk   = (int*)(Wf + off); off += B * TOPK;
    float* inp    = Wf + off; off += (size_t)B * 6 * D;
    float* xp     = Wf + off; off += (size_t)B * 6 * H;
    float* gate   = Wf + off; off += (size_t)B * H;

    k_center<<<1, 64, 0, stream>>>(sw, H, center);
    k_qprep<<<B, 128, 0, stream>>>(query, Aglob, B, D);
    k_sim_topk<<<ntiles, 256, 0, stream>>>(Aglob, mem, coords, center, candV, candI, M, D);
    k_merge<<<B, 256, 0, stream>>>(candV, candI, ntiles, B, topk);
    k_gather<<<B * 6, D / 4, 0, stream>>>(query, mem, topk, inp, D);
    // xp[b*6+t][H] = INP @ W_ih^T + b_ih
    k_tail_gemm<<<dim3(B * 6 / 64, H / 64), 256, 0, stream>>>(inp, W_ih, b_ih, xp, D, H, 0);
    // gate = sigmoid(q @ gate_W^T + gate_b)
    k_tail_gemm<<<dim3(B / 64, H / 64), 256, 0, stream>>>(query, gate_W, gate_b, gate, D, H, 1);
    // fused RNN (6 steps) + final gate mix
    k_rnn<<<B / 4, 256, 0, stream>>>(xp, W_hh, b_hh, gate, (float*)d_out, H);
}

// Round 4
// 1320.527 us; speedup vs baseline: 1.2803x; 1.2803x over previous
//
#include <hip/hip_runtime.h>
#include <math.h>

#define EPSC 1e-8f
#define TOPK 5

typedef _Float16 half8_t __attribute__((ext_vector_type(8)));
typedef float f32x4 __attribute__((ext_vector_type(4)));

__device__ __forceinline__ bool better(float va, int ia, float vb, int ib) {
    return (va > vb) || (va == vb && ia < ib);
}

// insert (v,gi) into sorted-desc top-5 (lv,li)
__device__ __forceinline__ void ins5(float v, int gi, float lv[TOPK], int li[TOPK]) {
    if (better(v, gi, lv[4], li[4])) {
        lv[4] = v; li[4] = gi;
#pragma unroll
        for (int p = 4; p > 0; --p) {
            if (better(lv[p], li[p], lv[p - 1], li[p - 1])) {
                float tv = lv[p]; lv[p] = lv[p - 1]; lv[p - 1] = tv;
                int ti = li[p]; li[p] = li[p - 1]; li[p - 1] = ti;
            }
        }
    }
}

// ---------------- center = mean(spatial_weights, axis=0) ----------------
__global__ void k_center(const float* __restrict__ sw, int H, float* __restrict__ center) {
    int tid = threadIdx.x;  // 64
    float sx = 0.f, sy = 0.f;
    for (int r = tid; r < H; r += 64) { sx += sw[2 * r]; sy += sw[2 * r + 1]; }
    for (int o = 32; o > 0; o >>= 1) { sx += __shfl_down(sx, o); sy += __shfl_down(sy, o); }
    if (tid == 0) { center[0] = sx / (float)H; center[1] = sy / (float)H; }
}

// ---------------- normalize queries + split to f16 hi/lo in plane-split frag-linear layout ----------------
// plane p (0=hi,1=lo) stride PS=16*KCH*512 f16;
// within plane: (qt*KCH + kc)*512 + (quad*16 + (b&15))*8 + j   where d = kc*32 + quad*8 + j
__global__ void k_qprep(const float* __restrict__ q, _Float16* __restrict__ Aglob, int B, int D) {
    int b = blockIdx.x;
    int tid = threadIdx.x;  // 128
    const int KCH = D >> 5;
    const int PS = 16 * KCH * 512;
    float ss = 0.f;
    for (int d = tid; d < D; d += 128) { float v = q[(size_t)b * D + d]; ss = fmaf(v, v, ss); }
    for (int o = 32; o > 0; o >>= 1) ss += __shfl_down(ss, o);
    __shared__ float w2[2];
    if ((tid & 63) == 0) w2[tid >> 6] = ss;
    __syncthreads();
    float inv = 1.f / fmaxf(sqrtf(w2[0] + w2[1]), EPSC);
    int qt = b >> 4, nl = b & 15;
    for (int d = tid; d < D; d += 128) {
        float v = q[(size_t)b * D + d] * inv;
        _Float16 hi = (_Float16)v;
        _Float16 lo = (_Float16)(v - (float)hi);
        int kc = d >> 5, r = d & 31, quad = r >> 3, j = r & 7;
        int idx = (qt * KCH + kc) * 512 + (quad * 16 + nl) * 8 + j;
        Aglob[idx] = hi;
        Aglob[PS + idx] = lo;
    }
}

// ---------------- main: split-f16 MFMA sim GEMM + fused norms + per-row top-5 ----------------
// grid: ceil(M/128), 256 threads (4 waves). Block: 256 queries x 128 mem rows (2 chunks of 64).
// R0-proven K-loop (JIT frags, stage inside barrier window, ~88 VGPR, no spill);
// halved epilogue overlay -> LDS 42496 B -> 3 blocks/CU.
__launch_bounds__(256, 3)
__global__ void k_sim_topk(const _Float16* __restrict__ Aglob, const float* __restrict__ mem,
                           const float* __restrict__ coords, const float* __restrict__ center,
                           float* __restrict__ candV, int* __restrict__ candI,
                           int M, int D) {
    __shared__ __align__(16) char smem[42496];
    _Float16* Ah = (_Float16*)smem;   // [16 qt][512]   16 KB
    _Float16* Al = Ah + 8192;         //                16 KB
    _Float16* Bh = Al + 8192;         // [4 ct][64][8]   4 KB
    _Float16* Bl = Bh + 2048;         //                 4 KB
    float* Cs = (float*)smem;         // epilogue overlay: 4 waves x 32 x 68 fp32 = 34816 B (over A/B)
    float* ssbuf  = (float*)(smem + 40960);  // 256
    float* colinv = ssbuf + 256;             // 64
    float* colact = colinv + 64;             // 64

    const int tid = threadIdx.x;
    const int lane = tid & 63, w = tid >> 6;
    const int nB = tid >> 2, qB = tid & 3;  // B staging: mem-row nB (0..63), k-octet qB
    const int KCH = D >> 5;
    const int PS = 16 * KCH * 512;
    const int n0 = blockIdx.x * 128;
    const float cx = center[0], cy = center[1];
    const int quad = lane >> 4, c15 = lane & 15;
    const int rr = lane & 31, hh = lane >> 5;

    float lv[TOPK]; int li[TOPK];
#pragma unroll
    for (int k = 0; k < TOPK; ++k) { lv[k] = -INFINITY; li[k] = 0x7fffffff; }

    for (int ch = 0; ch < 2; ++ch) {
        const int base = n0 + ch * 64;
        f32x4 acc[4][4];
#pragma unroll
        for (int rt = 0; rt < 4; ++rt)
#pragma unroll
            for (int ct = 0; ct < 4; ++ct) acc[rt][ct] = (f32x4){0.f, 0.f, 0.f, 0.f};
        float ss = 0.f;
        const int brow = base + nB;
        const bool bvalid = brow < M;

        for (int kc = 0; kc < KCH; ++kc) {
            __syncthreads();  // previous iter frag-reads / epilogue done
            // stage A (pure copy of frag-linear f16 planes): 2048 x 16B units
#pragma unroll
            for (int i = 0; i < 8; ++i) {
                int u = tid + i * 256;
                int p = u >> 10, rem = u & 1023, qt = rem >> 6, t = u & 63;
                *(float4*)(smem + (size_t)u * 16) =
                    *(const float4*)(Aglob + (size_t)p * PS + ((size_t)qt * KCH + kc) * 512 + t * 8);
            }
            // stage B: load fp32, split to f16 hi/lo, fused sum-of-squares
            {
                half8_t hv, lov;
                float vv[8];
                if (bvalid) {
                    const float* src = mem + (size_t)brow * D + kc * 32 + qB * 8;
                    float4 v0 = *(const float4*)src;
                    float4 v1 = *(const float4*)(src + 4);
                    vv[0] = v0.x; vv[1] = v0.y; vv[2] = v0.z; vv[3] = v0.w;
                    vv[4] = v1.x; vv[5] = v1.y; vv[6] = v1.z; vv[7] = v1.w;
                } else {
#pragma unroll
                    for (int j = 0; j < 8; ++j) vv[j] = 0.f;
                }
#pragma unroll
                for (int j = 0; j < 8; ++j) {
                    ss = fmaf(vv[j], vv[j], ss);
                    _Float16 h = (_Float16)vv[j];
                    hv[j] = h;
                    lov[j] = (_Float16)(vv[j] - (float)h);
                }
                int ct = nB >> 4, nl = nB & 15;
                int off = (ct * 64 + qB * 16 + nl) * 8;
                *(half8_t*)(Bh + off) = hv;
                *(half8_t*)(Bl + off) = lov;
            }
            __syncthreads();
            // fragments + MFMA (3 products per tile: hh, hl, lh) — JIT reads, low live-range
            half8_t ah[4], al[4], bh[4], bl[4];
#pragma unroll
            for (int rt = 0; rt < 4; ++rt) {
                int qt = w * 4 + rt;
                ah[rt] = *(half8_t*)(Ah + qt * 512 + lane * 8);
                al[rt] = *(half8_t*)(Al + qt * 512 + lane * 8);
            }
#pragma unroll
            for (int ct = 0; ct < 4; ++ct) {
                bh[ct] = *(half8_t*)(Bh + (ct * 64 + lane) * 8);
                bl[ct] = *(half8_t*)(Bl + (ct * 64 + lane) * 8);
            }
#pragma unroll
            for (int rt = 0; rt < 4; ++rt)
#pragma unroll
                for (int ct = 0; ct < 4; ++ct) {
                    acc[rt][ct] = __builtin_amdgcn_mfma_f32_16x16x32_f16(ah[rt], bh[ct], acc[rt][ct], 0, 0, 0);
                    acc[rt][ct] = __builtin_amdgcn_mfma_f32_16x16x32_f16(ah[rt], bl[ct], acc[rt][ct], 0, 0, 0);
                    acc[rt][ct] = __builtin_amdgcn_mfma_f32_16x16x32_f16(al[rt], bh[ct], acc[rt][ct], 0, 0, 0);
                }
        }
        // column stats
        ssbuf[tid] = ss;
        __syncthreads();  // also guarantees all frag-reads done before Cs overlay writes
        if (tid < 64) {
            float s = ssbuf[tid * 4] + ssbuf[tid * 4 + 1] + ssbuf[tid * 4 + 2] + ssbuf[tid * 4 + 3];
            colinv[tid] = 1.f / fmaxf(sqrtf(s), EPSC);
            int m = base + tid;
            float act = -INFINITY;
            if (m < M) {
                float dx = coords[2 * (size_t)m] - cx;
                float dy = coords[2 * (size_t)m + 1] - cy;
                act = 1.f / (1.f + sqrtf(dx * dx + dy * dy));
            }
            colact[tid] = act;
        }
        __syncthreads();

        // epilogue: two 32-row passes (halves LDS overlay); per pass each row scanned by
        // 2 lanes (32 cols each), lists merged via shfl_xor(32) with snapshot; owner absorbs.
        float* Cw = Cs + w * (32 * 68);
#pragma unroll
        for (int ps = 0; ps < 2; ++ps) {
#pragma unroll
            for (int rt2 = 0; rt2 < 2; ++rt2) {
                const int rt = 2 * ps + rt2;
#pragma unroll
                for (int ct = 0; ct < 4; ++ct) {
                    const int c = ct * 16 + c15;
                    const float inv = colinv[c], act = colact[c];
#pragma unroll
                    for (int i = 0; i < 4; ++i) {
                        Cw[(rt2 * 16 + quad * 4 + i) * 68 + c] = fmaf(acc[rt][ct][i], inv, act);
                    }
                }
            }
            // same-wave write->read: no barrier needed
            float tv5[TOPK]; int ti5[TOPK];
#pragma unroll
            for (int k = 0; k < TOPK; ++k) { tv5[k] = -INFINITY; ti5[k] = 0x7fffffff; }
            const float* Crow = Cw + rr * 68 + hh * 32;
            for (int j = 0; j < 32; ++j) {
                const int cc = (j + lane) & 31;
                ins5(Crow[cc], base + hh * 32 + cc, tv5, ti5);
            }
            // snapshot partner's list FIRST (both sides mutate during merge)
            float pv[TOPK]; int pi[TOPK];
#pragma unroll
            for (int k = 0; k < TOPK; ++k) {
                pv[k] = __shfl_xor(tv5[k], 32);
                pi[k] = __shfl_xor(ti5[k], 32);
            }
#pragma unroll
            for (int k = 0; k < TOPK; ++k) ins5(pv[k], pi[k], tv5, ti5);
            if (hh == ps) {  // owner lane: query offset = ps*32 + rr == lane
#pragma unroll
                for (int k = 0; k < TOPK; ++k) ins5(tv5[k], ti5[k], lv, li);
            }
        }
        __syncthreads();  // scan done before next chunk restages A/B (overlaps Cs)
    }
    // per-q candidates: q = w*64 + lane
    size_t cb = ((size_t)blockIdx.x * 256 + (w * 64 + lane)) * TOPK;
#pragma unroll
    for (int k = 0; k < TOPK; ++k) { candV[cb + k] = lv[k]; candI[cb + k] = li[k]; }
}

// ---------------- merge per-tile candidates -> global top-5 (sorted desc) ----------------
__global__ void k_merge(const float* __restrict__ candV, const int* __restrict__ candI,
                        int ntiles, int B, int* __restrict__ topk) {
    int b = blockIdx.x;
    int tid = threadIdx.x;  // 256
    float lv[TOPK]; int li[TOPK];
#pragma unroll
    for (int k = 0; k < TOPK; ++k) { lv[k] = -INFINITY; li[k] = 0x7fffffff; }
    for (int t = tid; t < ntiles; t += 256) {
        size_t base = ((size_t)t * B + b) * TOPK;
#pragma unroll
        for (int k = 0; k < TOPK; ++k) {
            float v = candV[base + k]; int gi = candI[base + k];
            if (better(v, gi, lv[4], li[4])) {
                lv[4] = v; li[4] = gi;
#pragma unroll
                for (int p = 4; p > 0; --p) {
                    if (better(lv[p], li[p], lv[p - 1], li[p - 1])) {
                        float tv = lv[p]; lv[p] = lv[p - 1]; lv[p - 1] = tv;
                        int ti = li[p]; li[p] = li[p - 1]; li[p - 1] = ti;
                    }
                }
            }
        }
    }
    __shared__ float sv[256 * TOPK];
    __shared__ int si[256 * TOPK];
#pragma unroll
    for (int k = 0; k < TOPK; ++k) { sv[tid * TOPK + k] = lv[k]; si[tid * TOPK + k] = li[k]; }
    __syncthreads();
    __shared__ float rv[256];
    __shared__ int ri[256], rp[256];
    for (int round = 0; round < TOPK; ++round) {
        float bv = -INFINITY; int bi = 0x7fffffff, bp = -1;
        for (int p = tid; p < 256 * TOPK; p += 256) {
            if (better(sv[p], si[p], bv, bi)) { bv = sv[p]; bi = si[p]; bp = p; }
        }
        rv[tid] = bv; ri[tid] = bi; rp[tid] = bp;
        __syncthreads();
        for (int st = 128; st > 0; st >>= 1) {
            if (tid < st) {
                if (better(rv[tid + st], ri[tid + st], rv[tid], ri[tid])) {
                    rv[tid] = rv[tid + st]; ri[tid] = ri[tid + st]; rp[tid] = rp[tid + st];
                }
            }
            __syncthreads();
        }
        if (tid == 0) {
            topk[b * TOPK + round] = ri[0];
            sv[rp[0]] = -INFINITY;
            si[rp[0]] = 0x7fffffff;
        }
        __syncthreads();
    }
}

// ---------------- gather RNN inputs: INP[b*6+t][D] ----------------
__global__ void k_gather(const float* __restrict__ q, const float* __restrict__ mem,
                         const int* __restrict__ topk, float* __restrict__ inp, int D) {
    int r = blockIdx.x;          // 0..B*6-1
    int b = r / 6, t = r - b * 6;
    int tid = threadIdx.x;       // 96 (D/4)
    const float* src = (t == 0) ? (q + (size_t)b * D)
                                : (mem + (size_t)topk[b * TOPK + (t - 1)] * D);
    *(float4*)&inp[(size_t)r * D + tid * 4] = *(const float4*)&src[tid * 4];
}

// ---------------- generic 64x64-tile fp32 GEMM: C = act(A @ W^T + bias) ----------------
// mode 0: dst = v (xproj);  mode 1: dst = sigmoid(v) (gate)
__launch_bounds__(256)
__global__ void k_tail_gemm(const float* __restrict__ A, const float* __restrict__ W,
                            const float* __restrict__ bias,
                            float* __restrict__ dst, int K, int ldc, int mode) {
    __shared__ float As[16 * 68], Ws[16 * 68];
    const int r0 = blockIdx.x * 64, c0 = blockIdx.y * 64;
    const int tid = threadIdx.x;
    float acc[4][4];
#pragma unroll
    for (int i = 0; i < 4; ++i)
#pragma unroll
        for (int j = 0; j < 4; ++j) acc[i][j] = 0.f;
    const int lr = tid >> 2, lk4 = (tid & 3) * 4;
    for (int k0 = 0; k0 < K; k0 += 16) {
        __syncthreads();
        float4 av = *(const float4*)&A[(size_t)(r0 + lr) * K + k0 + lk4];
        float4 wv = *(const float4*)&W[(size_t)(c0 + lr) * K + k0 + lk4];
        As[(lk4 + 0) * 68 + lr] = av.x; As[(lk4 + 1) * 68 + lr] = av.y;
        As[(lk4 + 2) * 68 + lr] = av.z; As[(lk4 + 3) * 68 + lr] = av.w;
        Ws[(lk4 + 0) * 68 + lr] = wv.x; Ws[(lk4 + 1) * 68 + lr] = wv.y;
        Ws[(lk4 + 2) * 68 + lr] = wv.z; Ws[(lk4 + 3) * 68 + lr] = wv.w;
        __syncthreads();
#pragma unroll
        for (int k = 0; k < 16; ++k) {
            float4 a4 = *(float4*)&As[k * 68 + (tid >> 4) * 4];
            float4 b4 = *(float4*)&Ws[k * 68 + (tid & 15) * 4];
            float a[4] = {a4.x, a4.y, a4.z, a4.w};
            float bb[4] = {b4.x, b4.y, b4.z, b4.w};
#pragma unroll
            for (int i = 0; i < 4; ++i)
#pragma unroll
                for (int j = 0; j < 4; ++j) acc[i][j] = fmaf(a[i], bb[j], acc[i][j]);
        }
    }
    const int tr = (tid >> 4) * 4, tc = (tid & 15) * 4;
#pragma unroll
    for (int i = 0; i < 4; ++i) {
        int r = r0 + tr + i;
#pragma unroll
        for (int j = 0; j < 4; ++j) {
            int c = c0 + tc + j;
            float v = acc[i][j] + bias[c];
            dst[(size_t)r * ldc + c] = (mode == 1) ? 1.f / (1.f + expf(-v)) : v;
        }
    }
}

// ---------------- fused 6-step RNN + gate mix (row-independent recurrence) ----------------
// grid: B/4 blocks, 256 threads (4 waves). Block rows [blk*4, +4).
// wave w owns cols [w*128, w*128+128); lane owns 2 cols c = w*128 + lane*2.
__launch_bounds__(256)
__global__ void k_rnn(const float* __restrict__ xp, const float* __restrict__ W_hh,
                      const float* __restrict__ b_hh, const float* __restrict__ gate,
                      float* __restrict__ out, int H) {
    __shared__ float hs[4][512];
    const int tid = threadIdx.x, lane = tid & 63, w = tid >> 6;
    const int b0 = blockIdx.x * 4;
    const int c0 = w * 128 + lane * 2;
    const float bh0 = b_hh[c0], bh1 = b_hh[c0 + 1];
    const float* w0p = W_hh + (size_t)c0 * H;
    const float* w1p = w0p + H;
    for (int t = 0; t < 6; ++t) {
        float acc[4][2];
#pragma unroll
        for (int r = 0; r < 4; ++r) {
            const float* xr = xp + ((size_t)(b0 + r) * 6 + t) * H;
            acc[r][0] = xr[c0] + bh0;
            acc[r][1] = xr[c0 + 1] + bh1;
        }
        if (t > 0) {
            for (int k = 0; k < H; k += 4) {
                float4 a0 = *(const float4*)(w0p + k);
                float4 a1 = *(const float4*)(w1p + k);
#pragma unroll
                for (int r = 0; r < 4; ++r) {
                    float4 h4 = *(const float4*)&hs[r][k];
                    acc[r][0] = fmaf(h4.x, a0.x, acc[r][0]);
                    acc[r][0] = fmaf(h4.y, a0.y, acc[r][0]);
                    acc[r][0] = fmaf(h4.z, a0.z, acc[r][0]);
                    acc[r][0] = fmaf(h4.w, a0.w, acc[r][0]);
                    acc[r][1] = fmaf(h4.x, a1.x, acc[r][1]);
                    acc[r][1] = fmaf(h4.y, a1.y, acc[r][1]);
                    acc[r][1] = fmaf(h4.z, a1.z, acc[r][1]);
                    acc[r][1] = fmaf(h4.w, a1.w, acc[r][1]);
                }
            }
        }
        __syncthreads();  // all reads of hs (state t-1) done before overwrite
        if (t < 5) {
#pragma unroll
            for (int r = 0; r < 4; ++r) {
                hs[r][c0]     = tanhf(acc[r][0]);
                hs[r][c0 + 1] = tanhf(acc[r][1]);
            }
        } else {
#pragma unroll
            for (int r = 0; r < 4; ++r) {
                const int b = b0 + r;
                const float* xq = xp + ((size_t)b * 6 + 0) * H;
#pragma unroll
                for (int j = 0; j < 2; ++j) {
                    float hn = tanhf(acc[r][j]);
                    float g = gate[(size_t)b * H + c0 + j];
                    out[(size_t)b * H + c0 + j] = g * hn + (1.f - g) * xq[c0 + j];
                }
            }
        }
        __syncthreads();  // new hs visible before next step's reads
    }
}

extern "C" void kernel_launch(void* const* d_in, const int* in_sizes, int n_in,
                              void* d_out, int out_size, void* d_ws, size_t ws_size,
                              hipStream_t stream) {
    const float* query  = (const float*)d_in[0];
    const float* mem    = (const float*)d_in[1];
    const float* coords = (const float*)d_in[2];
    const float* sw     = (const float*)d_in[3];
    const float* W_ih   = (const float*)d_in[4];
    const float* b_ih   = (const float*)d_in[5];
    const float* W_hh   = (const float*)d_in[6];
    const float* b_hh   = (const float*)d_in[7];
    const float* gate_W = (const float*)d_in[8];
    const float* gate_b = (const float*)d_in[9];

    const int H = in_sizes[5];           // 512
    const int D = in_sizes[4] / H;       // 384
    const int B = in_sizes[0] / D;       // 256
    const int M = in_sizes[1] / D;       // 200000
    const int KCH = D >> 5;
    const int ntiles = (M + 127) / 128;  // 1563

    float* Wf = (float*)d_ws;
    size_t off = 0;
    _Float16* Aglob = (_Float16*)Wf;     off += (size_t)2 * 16 * KCH * 512 / 2;  // f16 elems /2 = floats
    float* center = Wf + off; off += 4;
    float* candV  = Wf + off; off += (size_t)ntiles * B * TOPK;
    int*   candI  = (int*)(Wf + off); off += (size_t)ntiles * B * TOPK;
    int*   topk   = (int*)(Wf + off); off += B * TOPK;
    float* inp    = Wf + off; off += (size_t)B * 6 * D;
    float* xp     = Wf + off; off += (size_t)B * 6 * H;
    float* gate   = Wf + off; off += (size_t)B * H;

    k_center<<<1, 64, 0, stream>>>(sw, H, center);
    k_qprep<<<B, 128, 0, stream>>>(query, Aglob, B, D);
    k_sim_topk<<<ntiles, 256, 0, stream>>>(Aglob, mem, coords, center, candV, candI, M, D);
    k_merge<<<B, 256, 0, stream>>>(candV, candI, ntiles, B, topk);
    k_gather<<<B * 6, D / 4, 0, stream>>>(query, mem, topk, inp, D);
    // xp[b*6+t][H] = INP @ W_ih^T + b_ih
    k_tail_gemm<<<dim3(B * 6 / 64, H / 64), 256, 0, stream>>>(inp, W_ih, b_ih, xp, D, H, 0);
    // gate = sigmoid(q @ gate_W^T + gate_b)
    k_tail_gemm<<<dim3(B / 64, H / 64), 256, 0, stream>>>(query, gate_W, gate_b, gate, D, H, 1);
    // fused RNN (6 steps) + final gate mix
    k_rnn<<<B / 4, 256, 0, stream>>>(xp, W_hh, b_hh, gate, (float*)d_out, H);
}